// Round 1
// baseline (594.971 us; speedup 1.0000x reference)
//
#include <hip/hip_runtime.h>

constexpr int N_SRC = 100000;
constexpr int N_DST = 100000;
constexpr int E     = 1600000;
constexpr int D     = 64;
constexpr float LN_EPS = 1e-5f;

// ---------------------------------------------------------------------------
// k1: FiLM GEMM. One thread per row. feat row in 64 VGPRs; weights fetched as
// wave-uniform s_load_dwordx4 (address depends only on uniform loop indices),
// so the inner loop is pure v_fmac_f32 with an SGPR operand. No LDS.
// ---------------------------------------------------------------------------
__global__ __launch_bounds__(256) void k_film(const float* __restrict__ feat,
                                              const float* __restrict__ Ww,   // [64][64]
                                              const float* __restrict__ Fw,   // [64][128]
                                              float* __restrict__ msg) {
    const int row = blockIdx.x * 256 + threadIdx.x;
    const bool valid = row < N_SRC;
    const int r = valid ? row : (N_SRC - 1);

    float f[D];
    const float4* frow = reinterpret_cast<const float4*>(feat + (size_t)r * D);
#pragma unroll
    for (int q = 0; q < D / 4; ++q) {
        float4 v = frow[q];
        f[4 * q + 0] = v.x; f[4 * q + 1] = v.y;
        f[4 * q + 2] = v.z; f[4 * q + 3] = v.w;
    }

    float4* mrow = reinterpret_cast<float4*>(msg + (size_t)r * D);

    for (int jb = 0; jb < D / 4; ++jb) {      // 16 iterations, 4 output cols each
        float am0 = 0.f, am1 = 0.f, am2 = 0.f, am3 = 0.f;
        float ag0 = 0.f, ag1 = 0.f, ag2 = 0.f, ag3 = 0.f;
        float ab0 = 0.f, ab1 = 0.f, ab2 = 0.f, ab3 = 0.f;
#pragma unroll
        for (int k = 0; k < D; ++k) {
            const float4 w = *reinterpret_cast<const float4*>(Ww + k * D + jb * 4);
            const float4 g = *reinterpret_cast<const float4*>(Fw + k * 2 * D + jb * 4);
            const float4 b = *reinterpret_cast<const float4*>(Fw + k * 2 * D + D + jb * 4);
            const float fv = f[k];
            am0 = fmaf(fv, w.x, am0); am1 = fmaf(fv, w.y, am1);
            am2 = fmaf(fv, w.z, am2); am3 = fmaf(fv, w.w, am3);
            ag0 = fmaf(fv, g.x, ag0); ag1 = fmaf(fv, g.y, ag1);
            ag2 = fmaf(fv, g.z, ag2); ag3 = fmaf(fv, g.w, ag3);
            ab0 = fmaf(fv, b.x, ab0); ab1 = fmaf(fv, b.y, ab1);
            ab2 = fmaf(fv, b.z, ab2); ab3 = fmaf(fv, b.w, ab3);
        }
        float4 o;
        o.x = fmaxf(fmaf(ag0, am0, ab0), 0.f);
        o.y = fmaxf(fmaf(ag1, am1, ab1), 0.f);
        o.z = fmaxf(fmaf(ag2, am2, ab2), 0.f);
        o.w = fmaxf(fmaf(ag3, am3, ab3), 0.f);
        if (valid) mrow[jb] = o;
    }
}

// ---------------------------------------------------------------------------
// k2: edge scatter. One wave per 4 edges; lane = feature. Coalesced 256B
// gather of msg[src], atomicAdd into out[dst] (out pre-zeroed).
// ---------------------------------------------------------------------------
constexpr int EDGES_PER_WAVE = 4;

__global__ __launch_bounds__(256) void k_scatter(const float* __restrict__ msg,
                                                 const int* __restrict__ esrc,
                                                 const int* __restrict__ edst,
                                                 float* __restrict__ h) {
    const int lane = threadIdx.x & 63;
    const int wave = (blockIdx.x * 256 + threadIdx.x) >> 6;
    const size_t e0 = (size_t)wave * EDGES_PER_WAVE;

    const int4 s4 = *reinterpret_cast<const int4*>(esrc + e0);
    const int4 d4 = *reinterpret_cast<const int4*>(edst + e0);
    const int s0 = __builtin_amdgcn_readfirstlane(s4.x);
    const int s1 = __builtin_amdgcn_readfirstlane(s4.y);
    const int s2 = __builtin_amdgcn_readfirstlane(s4.z);
    const int s3 = __builtin_amdgcn_readfirstlane(s4.w);
    const int t0 = __builtin_amdgcn_readfirstlane(d4.x);
    const int t1 = __builtin_amdgcn_readfirstlane(d4.y);
    const int t2 = __builtin_amdgcn_readfirstlane(d4.z);
    const int t3 = __builtin_amdgcn_readfirstlane(d4.w);

    const float v0 = msg[(size_t)s0 * D + lane];
    const float v1 = msg[(size_t)s1 * D + lane];
    const float v2 = msg[(size_t)s2 * D + lane];
    const float v3 = msg[(size_t)s3 * D + lane];

    atomicAdd(h + (size_t)t0 * D + lane, v0);
    atomicAdd(h + (size_t)t1 * D + lane, v1);
    atomicAdd(h + (size_t)t2 * D + lane, v2);
    atomicAdd(h + (size_t)t3 * D + lane, v3);
}

// ---------------------------------------------------------------------------
// k3: LayerNorm over D=64, in place on d_out. One wave per row.
// ---------------------------------------------------------------------------
__global__ __launch_bounds__(256) void k_ln(float* __restrict__ h,
                                            const float* __restrict__ sc,
                                            const float* __restrict__ bi) {
    const int lane = threadIdx.x & 63;
    const int row = (blockIdx.x * 256 + threadIdx.x) >> 6;

    float v = h[(size_t)row * D + lane];
    float s = v;
#pragma unroll
    for (int off = 32; off > 0; off >>= 1) s += __shfl_xor(s, off);
    const float mu = s * (1.0f / D);
    const float dv = v - mu;
    float s2 = dv * dv;
#pragma unroll
    for (int off = 32; off > 0; off >>= 1) s2 += __shfl_xor(s2, off);
    const float var = s2 * (1.0f / D);
    const float o = dv * rsqrtf(var + LN_EPS) * sc[lane] + bi[lane];
    h[(size_t)row * D + lane] = o;
}

// ---------------------------------------------------------------------------
extern "C" void kernel_launch(void* const* d_in, const int* in_sizes, int n_in,
                              void* d_out, int out_size, void* d_ws, size_t ws_size,
                              hipStream_t stream) {
    const float* feat = (const float*)d_in[0];
    const int*   esrc = (const int*)d_in[1];
    const int*   edst = (const int*)d_in[2];
    const float* Ww   = (const float*)d_in[3];
    const float* Fw   = (const float*)d_in[4];
    const float* sc   = (const float*)d_in[5];
    const float* bi   = (const float*)d_in[6];
    float* out = (float*)d_out;
    float* msg = (float*)d_ws;   // 100000*64*4 = 25.6 MB scratch

    // out is re-poisoned before every timed call -> zero it (accumulator).
    hipMemsetAsync(d_out, 0, (size_t)N_DST * D * sizeof(float), stream);

    k_film<<<(N_SRC + 255) / 256, 256, 0, stream>>>(feat, Ww, Fw, msg);

    // waves = E/4 = 400000; blocks = waves/4 = 100000 (exact)
    k_scatter<<<E / (EDGES_PER_WAVE * 4), 256, 0, stream>>>(msg, esrc, edst, out);

    // 25000 blocks * 4 waves = 100000 rows (exact)
    k_ln<<<(N_DST * D) / 256, 256, 0, stream>>>(out, sc, bi);
}

// Round 2
// 409.633 us; speedup vs baseline: 1.4524x; 1.4524x over previous
//
#include <hip/hip_runtime.h>

constexpr int N_SRC = 100000;
constexpr int N_DST = 100000;
constexpr int E     = 1600000;
constexpr int D     = 64;
constexpr float LN_EPS = 1e-5f;
constexpr int NB = (N_DST + 255) / 256;   // 391 scan blocks

// ---------------------------------------------------------------------------
// k1: FiLM GEMM. Weights staged in LDS (48 KB); inner loop = uniform-address
// ds_read_b128 (broadcast) + v_fmac_f32. One thread per row.
// ---------------------------------------------------------------------------
__global__ __launch_bounds__(256) void k_film(const float* __restrict__ feat,
                                              const float* __restrict__ Ww,   // [64][64]
                                              const float* __restrict__ Fw,   // [64][128]
                                              float* __restrict__ msg) {
    __shared__ float Wl[64 * 64];
    __shared__ float Fl[64 * 128];

    {   // cooperative vectorized staging: 4096+8192 floats = 1024+2048 float4
        const float4* Wg = reinterpret_cast<const float4*>(Ww);
        const float4* Fg = reinterpret_cast<const float4*>(Fw);
        float4* Wd = reinterpret_cast<float4*>(Wl);
        float4* Fd = reinterpret_cast<float4*>(Fl);
        for (int i = threadIdx.x; i < 1024; i += 256) Wd[i] = Wg[i];
        for (int i = threadIdx.x; i < 2048; i += 256) Fd[i] = Fg[i];
    }
    __syncthreads();

    const int row = blockIdx.x * 256 + threadIdx.x;
    const bool valid = row < N_SRC;
    const int r = valid ? row : (N_SRC - 1);

    float f[D];
    const float4* frow = reinterpret_cast<const float4*>(feat + (size_t)r * D);
#pragma unroll
    for (int q = 0; q < D / 4; ++q) {
        float4 v = frow[q];
        f[4 * q + 0] = v.x; f[4 * q + 1] = v.y;
        f[4 * q + 2] = v.z; f[4 * q + 3] = v.w;
    }

    float4* mrow = reinterpret_cast<float4*>(msg + (size_t)r * D);

    for (int jb = 0; jb < D / 4; ++jb) {
        float am0 = 0.f, am1 = 0.f, am2 = 0.f, am3 = 0.f;
        float ag0 = 0.f, ag1 = 0.f, ag2 = 0.f, ag3 = 0.f;
        float ab0 = 0.f, ab1 = 0.f, ab2 = 0.f, ab3 = 0.f;
#pragma unroll
        for (int k = 0; k < D; ++k) {
            const float4 w = *reinterpret_cast<const float4*>(&Wl[k * D + jb * 4]);
            const float4 g = *reinterpret_cast<const float4*>(&Fl[k * 2 * D + jb * 4]);
            const float4 b = *reinterpret_cast<const float4*>(&Fl[k * 2 * D + D + jb * 4]);
            const float fv = f[k];
            am0 = fmaf(fv, w.x, am0); am1 = fmaf(fv, w.y, am1);
            am2 = fmaf(fv, w.z, am2); am3 = fmaf(fv, w.w, am3);
            ag0 = fmaf(fv, g.x, ag0); ag1 = fmaf(fv, g.y, ag1);
            ag2 = fmaf(fv, g.z, ag2); ag3 = fmaf(fv, g.w, ag3);
            ab0 = fmaf(fv, b.x, ab0); ab1 = fmaf(fv, b.y, ab1);
            ab2 = fmaf(fv, b.z, ab2); ab3 = fmaf(fv, b.w, ab3);
        }
        float4 o;
        o.x = fmaxf(fmaf(ag0, am0, ab0), 0.f);
        o.y = fmaxf(fmaf(ag1, am1, ab1), 0.f);
        o.z = fmaxf(fmaf(ag2, am2, ab2), 0.f);
        o.w = fmaxf(fmaf(ag3, am3, ab3), 0.f);
        if (valid) mrow[jb] = o;
    }
}

// ---------------------------------------------------------------------------
// CSR build: histogram -> 3-kernel exclusive scan -> fill
// ---------------------------------------------------------------------------
__global__ __launch_bounds__(256) void k_hist(const int* __restrict__ edst,
                                              int* __restrict__ counts) {
    const int e = blockIdx.x * 256 + threadIdx.x;
    if (e < E) atomicAdd(&counts[edst[e]], 1);
}

__global__ __launch_bounds__(256) void k_scan1(const int* __restrict__ counts,
                                               int* __restrict__ offs,
                                               int* __restrict__ partials) {
    const int i = blockIdx.x * 256 + threadIdx.x;
    const int lane = threadIdx.x & 63;
    const int wid = threadIdx.x >> 6;
    const int v = (i < N_DST) ? counts[i] : 0;
    int x = v;
#pragma unroll
    for (int o = 1; o < 64; o <<= 1) { int y = __shfl_up(x, o); if (lane >= o) x += y; }
    __shared__ int wsum[4];
    if (lane == 63) wsum[wid] = x;
    __syncthreads();
    int add = 0;
    for (int w = 0; w < wid; ++w) add += wsum[w];
    const int incl = x + add;
    if (i < N_DST) offs[i] = incl - v;                    // block-local exclusive
    if (threadIdx.x == 255) partials[blockIdx.x] = incl;  // block total
}

__global__ __launch_bounds__(512) void k_scan2(int* __restrict__ partials) {
    const int t = threadIdx.x;
    const int lane = t & 63;
    const int wid = t >> 6;
    const int v = (t < NB) ? partials[t] : 0;
    int x = v;
#pragma unroll
    for (int o = 1; o < 64; o <<= 1) { int y = __shfl_up(x, o); if (lane >= o) x += y; }
    __shared__ int wsum[8];
    if (lane == 63) wsum[wid] = x;
    __syncthreads();
    int add = 0;
    for (int w = 0; w < wid; ++w) add += wsum[w];
    const int incl = x + add;
    if (t < NB) partials[t] = incl - v;                   // exclusive block offsets
}

__global__ __launch_bounds__(256) void k_scan3(int* __restrict__ offs,
                                               const int* __restrict__ partials,
                                               int* __restrict__ cursor) {
    const int i = blockIdx.x * 256 + threadIdx.x;
    if (i < N_DST) {
        const int o = offs[i] + partials[blockIdx.x];
        offs[i] = o;
        cursor[i] = o;
    }
    if (i == 0) offs[N_DST] = E;
}

__global__ __launch_bounds__(256) void k_fill(const int* __restrict__ esrc,
                                              const int* __restrict__ edst,
                                              int* __restrict__ cursor,
                                              int* __restrict__ csr) {
    const int e = blockIdx.x * 256 + threadIdx.x;
    if (e < E) {
        const int d = edst[e];
        const int pos = atomicAdd(&cursor[d], 1);
        csr[pos] = esrc[e];
    }
}

// ---------------------------------------------------------------------------
// k_gather_ln: one wave per dst row. Lane-parallel edge-id load + shfl
// broadcast; coalesced 256B gathers of msg (L3-resident); fused LayerNorm.
// No atomics, out written exactly once.
// ---------------------------------------------------------------------------
__global__ __launch_bounds__(256) void k_gather_ln(const float* __restrict__ msg,
                                                   const int* __restrict__ csr,
                                                   const int* __restrict__ offs,
                                                   const float* __restrict__ sc,
                                                   const float* __restrict__ bi,
                                                   float* __restrict__ out) {
    const int lane = threadIdx.x & 63;
    const int row = (blockIdx.x * 256 + threadIdx.x) >> 6;
    if (row >= N_DST) return;

    const int start = offs[row];
    const int end   = offs[row + 1];

    float a0 = 0.f, a1 = 0.f, a2 = 0.f, a3 = 0.f;
    for (int base = start; base < end; base += 64) {
        const int n = min(64, end - base);
        const int id = (lane < n) ? csr[base + lane] : 0;
        int i = 0;
        for (; i + 4 <= n; i += 4) {
            const int s0 = __shfl(id, i + 0);
            const int s1 = __shfl(id, i + 1);
            const int s2 = __shfl(id, i + 2);
            const int s3 = __shfl(id, i + 3);
            a0 += msg[(size_t)s0 * D + lane];
            a1 += msg[(size_t)s1 * D + lane];
            a2 += msg[(size_t)s2 * D + lane];
            a3 += msg[(size_t)s3 * D + lane];
        }
        for (; i < n; ++i) a0 += msg[(size_t)__shfl(id, i) * D + lane];
    }
    const float v = (a0 + a1) + (a2 + a3);

    // LayerNorm over the 64 lanes
    float s = v;
#pragma unroll
    for (int off = 32; off > 0; off >>= 1) s += __shfl_xor(s, off);
    const float mu = s * (1.0f / D);
    const float dv = v - mu;
    float s2 = dv * dv;
#pragma unroll
    for (int off = 32; off > 0; off >>= 1) s2 += __shfl_xor(s2, off);
    const float var = s2 * (1.0f / D);
    out[(size_t)row * D + lane] = dv * rsqrtf(var + LN_EPS) * sc[lane] + bi[lane];
}

// ---------------------------------------------------------------------------
extern "C" void kernel_launch(void* const* d_in, const int* in_sizes, int n_in,
                              void* d_out, int out_size, void* d_ws, size_t ws_size,
                              hipStream_t stream) {
    const float* feat = (const float*)d_in[0];
    const int*   esrc = (const int*)d_in[1];
    const int*   edst = (const int*)d_in[2];
    const float* Ww   = (const float*)d_in[3];
    const float* Fw   = (const float*)d_in[4];
    const float* sc   = (const float*)d_in[5];
    const float* bi   = (const float*)d_in[6];
    float* out = (float*)d_out;

    // workspace layout
    char* ws = (char*)d_ws;
    float* msg     = (float*)(ws);                               // 25.6 MB
    int*   csr     = (int*)(ws + 26u * 1024 * 1024);             // 6.4 MB
    int*   counts  = (int*)(ws + 33u * 1024 * 1024);             // 400 KB
    int*   offs    = (int*)(ws + 34u * 1024 * 1024);             // 400 KB + 4
    int*   cursor  = (int*)(ws + 35u * 1024 * 1024);             // 400 KB
    int*   partials= (int*)(ws + 36u * 1024 * 1024);             // 1.6 KB

    hipMemsetAsync(counts, 0, N_DST * sizeof(int), stream);

    k_film<<<(N_SRC + 255) / 256, 256, 0, stream>>>(feat, Ww, Fw, msg);
    k_hist<<<(E + 255) / 256, 256, 0, stream>>>(edst, counts);
    k_scan1<<<NB, 256, 0, stream>>>(counts, offs, partials);
    k_scan2<<<1, 512, 0, stream>>>(partials);
    k_scan3<<<NB, 256, 0, stream>>>(offs, partials, cursor);
    k_fill<<<(E + 255) / 256, 256, 0, stream>>>(esrc, edst, cursor, csr);
    k_gather_ln<<<(N_DST + 3) / 4, 256, 0, stream>>>(msg, csr, offs, sc, bi, out);
}